// Round 1
// baseline (562.674 us; speedup 1.0000x reference)
//
#include <hip/hip_runtime.h>
#include <hip/hip_bf16.h>

#define N_AL 9
#define N_EN 10
#define D_OWN 96
#define D_AL 64
#define D_EN 65
#define BROWS 65536

typedef __attribute__((ext_vector_type(8))) short short8;
typedef __attribute__((ext_vector_type(4))) float f32x4;

static __device__ __forceinline__ short f2bf(float f) {
    union { float f; unsigned u; } v; v.f = f;
    unsigned r = v.u + 0x7FFFu + ((v.u >> 16) & 1u);   // round-to-nearest-even
    return (short)(r >> 16);
}

static __device__ __forceinline__ short8 packbf8(f32x4 a, f32x4 b) {
    short8 r;
    r[0] = f2bf(a[0]); r[1] = f2bf(a[1]); r[2] = f2bf(a[2]); r[3] = f2bf(a[3]);
    r[4] = f2bf(b[0]); r[5] = f2bf(b[1]); r[6] = f2bf(b[2]); r[7] = f2bf(b[3]);
    return r;
}

// Pre-pack combined [K][256] weights (W0 cols 0..127, W1 cols 128..255) into
// per-lane MFMA B-fragments: bpack[((tile*KS + ks)*64 + lane)*8 + i]
//   = W[k = ks*32 + (lane>>4)*8 + i][col = tile*16 + (lane&15)]  (0 if k>=K)
static __device__ void stage_phase(const float* __restrict__ W0, const float* __restrict__ W1,
                                   const float* __restrict__ b0, const float* __restrict__ b1,
                                   int K, int KS, short* bpack, float* bias, int tid)
{
    const int nfrag = 16 * KS * 64;
    for (int f = tid; f < nfrag; f += 256) {
        int tile = f / (KS * 64);
        int rem  = f - tile * (KS * 64);
        int ks   = rem >> 6;
        int lane = rem & 63;
        int col  = tile * 16 + (lane & 15);
        int k0   = ks * 32 + (lane >> 4) * 8;
        const float* W = (col < 128) ? W0 : W1;
        int c = col & 127;
        short8 v;
        #pragma unroll
        for (int i = 0; i < 8; ++i) {
            int k = k0 + i;
            float x = (k < K) ? W[k * 128 + c] : 0.0f;
            v[i] = f2bf(x);
        }
        *(short8*)(bpack + (size_t)f * 8) = v;
    }
    bias[tid & 255] = ((tid & 255) < 128) ? b0[tid & 255] : b1[(tid & 255) - 128];
}

// One 16x256 GEMM tile: acc[t] initialized from bias, K = KS*32 steps.
template <int KS>
static __device__ __forceinline__ void gemm16(const short8* afr, const short* bpack,
                                              const float* bias, int lane, f32x4* acc)
{
    const int lrow = lane & 15;
    #pragma unroll
    for (int t = 0; t < 16; ++t) {
        float bz = bias[t * 16 + lrow];
        acc[t][0] = bz; acc[t][1] = bz; acc[t][2] = bz; acc[t][3] = bz;
    }
    #pragma unroll
    for (int ks = 0; ks < KS; ++ks) {
        #pragma unroll
        for (int t = 0; t < 16; ++t) {
            short8 bfr = *(const short8*)(bpack + (size_t)((t * KS + ks) * 64 + lane) * 8);
            acc[t] = __builtin_amdgcn_mfma_f32_16x16x32_bf16(afr[ks], bfr, acc[t], 0, 0, 0);
        }
    }
}

// Online attention accumulation for one entity.
// acc tiles 0..7 = K (cols 0..127), tiles 8..15 = V (cols 128..255).
// C layout: row = (lane>>4)*4 + r, col = tile*16 + (lane&15).
static __device__ __forceinline__ void attn_update(const float (&qf)[8][4], const f32x4 (&acc)[16],
                                                   float (&accn)[8][4], float (&accd)[4][4])
{
    const float scale = 0.17677669529663687f;  // 1/sqrt(32)
    #pragma unroll
    for (int h = 0; h < 4; ++h) {
        float p[4];
        #pragma unroll
        for (int r = 0; r < 4; ++r)
            p[r] = qf[2*h][r] * acc[2*h][r] + qf[2*h+1][r] * acc[2*h+1][r];
        // reduce over the 16 lanes holding this row's columns (masks stay in-group)
        #pragma unroll
        for (int m = 1; m <= 8; m <<= 1) {
            #pragma unroll
            for (int r = 0; r < 4; ++r)
                p[r] += __shfl_xor(p[r], m, 64);
        }
        #pragma unroll
        for (int r = 0; r < 4; ++r) {
            float s = __expf(p[r] * scale);   // energies ~N(0,1): no max-sub needed
            accd[h][r] += s;
            accn[2*h][r]   += s * acc[8 + 2*h][r];
            accn[2*h+1][r] += s * acc[8 + 2*h+1][r];
        }
    }
}

static __device__ __forceinline__ void write_attn(float* __restrict__ out, int orow, int coloff,
                                                  const float (&accn)[8][4], const float (&accd)[4][4],
                                                  int lrow)
{
    float inv[4][4];
    #pragma unroll
    for (int h = 0; h < 4; ++h)
        #pragma unroll
        for (int r = 0; r < 4; ++r)
            inv[h][r] = 1.0f / accd[h][r];
    #pragma unroll
    for (int t = 0; t < 8; ++t)
        #pragma unroll
        for (int r = 0; r < 4; ++r)
            out[(size_t)(orow + r) * 384 + coloff + t * 16 + lrow] = accn[t][r] * inv[t >> 1][r];
}

__global__ __launch_bounds__(256, 2)
void TrSFRNNAgent_fused(const float* __restrict__ own,
                        const float* __restrict__ ally,
                        const float* __restrict__ enemy,
                        const float* __restrict__ Wq,  const float* __restrict__ bq,
                        const float* __restrict__ Wak, const float* __restrict__ bak,
                        const float* __restrict__ Wav, const float* __restrict__ bav,
                        const float* __restrict__ Wek, const float* __restrict__ bek,
                        const float* __restrict__ Wev, const float* __restrict__ bev,
                        const float* __restrict__ Wown,const float* __restrict__ bown,
                        float* __restrict__ out)
{
    __shared__ short bpack[16 * 3 * 64 * 8];   // 48 KiB, max KS=3
    __shared__ float bias[256];

    const int tid  = threadIdx.x;
    const int lane = tid & 63;
    const int wid  = tid >> 6;
    const int row0 = blockIdx.x * 64 + wid * 16;   // wave's 16 rows
    const int lrow = lane & 15;                    // A row / C col within tile
    const int kgrp = lane >> 4;                    // A k-group / C row-group
    const int arow = row0 + lrow;                  // global row for A fragments
    const int orow = row0 + kgrp * 4;              // base global row for C frags

    f32x4 acc[16];
    float qf[8][4];

    // ---------------- Phase 0: own_obs -> q (cols 0..127) + own_feature ----------------
    stage_phase(Wq, Wown, bq, bown, D_OWN, 3, bpack, bias, tid);
    __syncthreads();
    {
        const float* ap = own + (size_t)arow * D_OWN;
        short8 afr[3];
        #pragma unroll
        for (int ks = 0; ks < 3; ++ks) {
            const f32x4* p = (const f32x4*)(ap + ks * 32 + kgrp * 8);
            afr[ks] = packbf8(p[0], p[1]);
        }
        gemm16<3>(afr, bpack, bias, lane, acc);
        #pragma unroll
        for (int t = 0; t < 8; ++t)
            #pragma unroll
            for (int r = 0; r < 4; ++r)
                qf[t][r] = acc[t][r];
        #pragma unroll
        for (int t = 0; t < 8; ++t)
            #pragma unroll
            for (int r = 0; r < 4; ++r)
                out[(size_t)(orow + r) * 384 + t * 16 + lrow] = acc[8 + t][r];
    }
    __syncthreads();

    // ---------------- Phase 1: allies (K=64, 2 k-steps) ----------------
    stage_phase(Wak, Wav, bak, bav, D_AL, 2, bpack, bias, tid);
    __syncthreads();
    {
        float accn[8][4] = {{0}}; float accd[4][4] = {{0}};
        for (int e = 0; e < N_AL; ++e) {
            const float* ap = ally + ((size_t)arow * N_AL + e) * D_AL;
            short8 afr[2];
            #pragma unroll
            for (int ks = 0; ks < 2; ++ks) {
                const f32x4* p = (const f32x4*)(ap + ks * 32 + kgrp * 8);
                afr[ks] = packbf8(p[0], p[1]);
            }
            gemm16<2>(afr, bpack, bias, lane, acc);
            attn_update(qf, acc, accn, accd);
        }
        write_attn(out, orow, 128, accn, accd, lrow);
    }
    __syncthreads();

    // ---------------- Phase 2: enemies (K=65 zero-padded to 3 k-steps) ----------------
    stage_phase(Wek, Wev, bek, bev, D_EN, 3, bpack, bias, tid);
    __syncthreads();
    {
        float accn[8][4] = {{0}}; float accd[4][4] = {{0}};
        for (int e = 0; e < N_EN; ++e) {
            const float* ap = enemy + ((size_t)arow * N_EN + e) * D_EN;  // 4B-aligned only
            short8 afr[3];
            #pragma unroll
            for (int ks = 0; ks < 2; ++ks) {
                #pragma unroll
                for (int i = 0; i < 8; ++i)
                    afr[ks][i] = f2bf(ap[ks * 32 + kgrp * 8 + i]);
            }
            {
                short8 v = (short8){0, 0, 0, 0, 0, 0, 0, 0};
                if (kgrp == 0) v[0] = f2bf(ap[64]);   // k=64 is the only valid lane/elem
                afr[2] = v;
            }
            gemm16<3>(afr, bpack, bias, lane, acc);
            attn_update(qf, acc, accn, accd);
        }
        write_attn(out, orow, 256, accn, accd, lrow);
    }
}

extern "C" void kernel_launch(void* const* d_in, const int* in_sizes, int n_in,
                              void* d_out, int out_size, void* d_ws, size_t ws_size,
                              hipStream_t stream)
{
    (void)in_sizes; (void)n_in; (void)d_ws; (void)ws_size; (void)out_size;
    dim3 grid(BROWS / 64), block(256);
    TrSFRNNAgent_fused<<<grid, block, 0, stream>>>(
        (const float*)d_in[0],  (const float*)d_in[1],  (const float*)d_in[2],
        (const float*)d_in[3],  (const float*)d_in[4],
        (const float*)d_in[5],  (const float*)d_in[6],
        (const float*)d_in[7],  (const float*)d_in[8],
        (const float*)d_in[9],  (const float*)d_in[10],
        (const float*)d_in[11], (const float*)d_in[12],
        (const float*)d_in[13], (const float*)d_in[14],
        (float*)d_out);
}

// Round 2
// 276.964 us; speedup vs baseline: 2.0316x; 2.0316x over previous
//
#include <hip/hip_runtime.h>
#include <hip/hip_bf16.h>
#include <stdint.h>

#define N_AL 9
#define N_EN 10
#define D_OWN 96
#define D_AL 64
#define D_EN 65
#define BROWS 65536

// ws byte layout
#define WS_P0 0        // 48 KB: phase0 frags (16 tiles x 3 ks x 64 lanes x 16B)
#define WS_B0 49152    // 1 KB : bias0 = [bq(128) | bown(128)] f32
#define WS_P1 50176    // 36 KB region: [bpack1 32768][bav 512][pad]
#define WS_P2 87040    // 36 KB region: [bpack2 32768][w64cat 1024][bev 512][pad]
#define REGION 36864

typedef __attribute__((ext_vector_type(8))) short short8;
typedef __attribute__((ext_vector_type(4))) float f32x4;
typedef __attribute__((address_space(1))) const unsigned guint;
typedef __attribute__((address_space(3))) unsigned luint;

static __device__ __forceinline__ unsigned cvtpk(float lo, float hi) {
    unsigned r;
    asm("v_cvt_pk_bf16_f32 %0, %1, %2" : "=v"(r) : "v"(lo), "v"(hi));
    return r;
}
static __device__ __forceinline__ float bflo(unsigned u) { return __builtin_bit_cast(float, u << 16); }
static __device__ __forceinline__ float bfhi(unsigned u) { return __builtin_bit_cast(float, u & 0xffff0000u); }

static __device__ __forceinline__ short8 pack8(f32x4 a, f32x4 b) {
    union { unsigned u[4]; short8 s; } t;
    t.u[0] = cvtpk(a[0], a[1]); t.u[1] = cvtpk(a[2], a[3]);
    t.u[2] = cvtpk(b[0], b[1]); t.u[3] = cvtpk(b[2], b[3]);
    return t.s;
}
static __device__ __forceinline__ short f2bf1(float x) { return (short)(cvtpk(x, 0.0f) & 0xffffu); }

// ---------------- weight packing kernel (runs once per launch, 31 blocks) ----------------
__global__ void pack_weights(const float* __restrict__ Wq,  const float* __restrict__ bq,
                             const float* __restrict__ Wak, const float* __restrict__ Wav,
                             const float* __restrict__ bav, const float* __restrict__ Wek,
                             const float* __restrict__ Wev, const float* __restrict__ bev,
                             const float* __restrict__ Wown,const float* __restrict__ bown,
                             char* __restrict__ ws)
{
    int id = blockIdx.x * 256 + threadIdx.x;
    if (id < 7168) {
        const float *W0, *W1; int KS; short* dst; int f;
        if (id < 3072)      { W0 = Wq;  W1 = Wown; KS = 3; dst = (short*)(ws + WS_P0); f = id; }
        else if (id < 5120) { W0 = Wak; W1 = Wav;  KS = 2; dst = (short*)(ws + WS_P1); f = id - 3072; }
        else                { W0 = Wek; W1 = Wev;  KS = 2; dst = (short*)(ws + WS_P2); f = id - 5120; }
        int lane = f & 63, ks = (f >> 6) % KS, tile = f / (KS * 64);
        int col = tile * 16 + (lane & 15), k0 = ks * 32 + (lane >> 4) * 8;
        const float* W = (col < 128) ? W0 : W1;
        int c = col & 127;
        short8 v;
        #pragma unroll
        for (int i = 0; i < 8; ++i) v[i] = f2bf1(W[(k0 + i) * 128 + c]);
        *(short8*)(dst + (size_t)f * 8) = v;
    } else if (id < 7936) {
        int j = id - 7168;
        float* b0  = (float*)(ws + WS_B0);
        float* bV1 = (float*)(ws + WS_P1 + 32768);
        float* w64 = (float*)(ws + WS_P2 + 32768);
        float* bV2 = (float*)(ws + WS_P2 + 33792);
        if      (j < 128) b0[j] = bq[j];
        else if (j < 256) b0[j] = bown[j - 128];
        else if (j < 384) w64[j - 256] = Wek[64 * 128 + (j - 256)];
        else if (j < 512) w64[j - 256] = Wev[64 * 128 + (j - 384)];
        else if (j < 640) bV1[j - 512] = bav[j - 512];
        else              bV2[j - 640] = bev[j - 640];
    }
}

// ---------------- 36 KB linear global->LDS stage (16B direct-to-LDS) ----------------
static __device__ __forceinline__ void stage36(const char* src, char* smem, int wid, int lane) {
    #pragma unroll
    for (int c = 0; c < 9; ++c) {
        int off = (wid * 9 + c) * 1024;
        __builtin_amdgcn_global_load_lds((guint*)(src + off + lane * 16),
                                         (luint*)(smem + off), 16, 0, 0);
    }
}

// ---------------- fused attention phase (head-pair split: acc stays at 4 tiles) ----------------
template <int NE, int DF, bool X64>
static __device__ __forceinline__ void attn_phase(
    const float* __restrict__ feats, const short* bpk, const float* w64lds,
    const float* bVlds, const unsigned* qq, float* __restrict__ out,
    int row0, int lane, int coloff)
{
    const int lrow = lane & 15, kgrp = lane >> 4;
    const int arow = row0 + lrow;
    float accn[2][4][4] = {{{0}}};
    float accd[4][4] = {{0}};
    float w64K[8], w64V[8];
    if (X64) {
        #pragma unroll
        for (int t = 0; t < 8; ++t) { w64K[t] = w64lds[t * 16 + lrow]; w64V[t] = w64lds[128 + t * 16 + lrow]; }
    }
    #pragma unroll 1
    for (int e = 0; e < NE; ++e) {
        const float* ap = feats + ((size_t)arow * NE + e) * DF;
        short8 afr[2];
        float x64f[4];
        if (!X64) {
            #pragma unroll
            for (int ks = 0; ks < 2; ++ks) {
                f32x4 a = *(const f32x4*)(ap + ks * 32 + kgrp * 8);
                f32x4 b = *(const f32x4*)(ap + ks * 32 + kgrp * 8 + 4);
                afr[ks] = pack8(a, b);
            }
        } else {
            #pragma unroll
            for (int ks = 0; ks < 2; ++ks) {
                float v[8];
                #pragma unroll
                for (int i = 0; i < 8; ++i) v[i] = ap[ks * 32 + kgrp * 8 + i];
                union { unsigned u[4]; short8 s; } t;
                t.u[0] = cvtpk(v[0], v[1]); t.u[1] = cvtpk(v[2], v[3]);
                t.u[2] = cvtpk(v[4], v[5]); t.u[3] = cvtpk(v[6], v[7]);
                afr[ks] = t.s;
            }
            #pragma unroll
            for (int r = 0; r < 4; ++r)
                x64f[r] = feats[((size_t)(row0 + kgrp * 4 + r) * NE + e) * DF + 64];
        }
        #pragma unroll
        for (int hp = 0; hp < 2; ++hp) {
            f32x4 acc4[4];
            #pragma unroll
            for (int j = 0; j < 4; ++j) {
                if (X64) { float w = w64K[4 * hp + j];
                    #pragma unroll
                    for (int r = 0; r < 4; ++r) acc4[j][r] = x64f[r] * w;
                } else {
                    #pragma unroll
                    for (int r = 0; r < 4; ++r) acc4[j][r] = 0.0f;
                }
            }
            #pragma unroll
            for (int ks = 0; ks < 2; ++ks)
                #pragma unroll
                for (int j = 0; j < 4; ++j) {
                    short8 bfr = *(const short8*)(bpk + (size_t)(((4 * hp + j) * 2 + ks) * 64 + lane) * 8);
                    acc4[j] = __builtin_amdgcn_mfma_f32_16x16x32_bf16(afr[ks], bfr, acc4[j], 0, 0, 0);
                }
            float p0[4] = {0, 0, 0, 0}, p1[4] = {0, 0, 0, 0};
            #pragma unroll
            for (int j = 0; j < 4; ++j) {
                int t = 4 * hp + j;
                float* pp = (j < 2) ? p0 : p1;
                #pragma unroll
                for (int pr = 0; pr < 2; ++pr) {
                    unsigned u = qq[t * 2 + pr];
                    pp[2 * pr]     += bflo(u) * acc4[j][2 * pr];
                    pp[2 * pr + 1] += bfhi(u) * acc4[j][2 * pr + 1];
                }
            }
            #pragma unroll
            for (int m = 1; m <= 8; m <<= 1) {
                #pragma unroll
                for (int r = 0; r < 4; ++r) {
                    p0[r] += __shfl_xor(p0[r], m, 64);
                    p1[r] += __shfl_xor(p1[r], m, 64);
                }
            }
            float s0[4], s1[4];
            #pragma unroll
            for (int r = 0; r < 4; ++r) {
                s0[r] = __expf(p0[r]); s1[r] = __expf(p1[r]);
                accd[2 * hp][r] += s0[r]; accd[2 * hp + 1][r] += s1[r];
            }
            #pragma unroll
            for (int j = 0; j < 4; ++j) {
                if (X64) { float w = w64V[4 * hp + j];
                    #pragma unroll
                    for (int r = 0; r < 4; ++r) acc4[j][r] = x64f[r] * w;
                } else {
                    #pragma unroll
                    for (int r = 0; r < 4; ++r) acc4[j][r] = 0.0f;
                }
            }
            #pragma unroll
            for (int ks = 0; ks < 2; ++ks)
                #pragma unroll
                for (int j = 0; j < 4; ++j) {
                    short8 bfr = *(const short8*)(bpk + (size_t)(((8 + 4 * hp + j) * 2 + ks) * 64 + lane) * 8);
                    acc4[j] = __builtin_amdgcn_mfma_f32_16x16x32_bf16(afr[ks], bfr, acc4[j], 0, 0, 0);
                }
            #pragma unroll
            for (int j = 0; j < 4; ++j) {
                const float* s = (j < 2) ? s0 : s1;
                #pragma unroll
                for (int r = 0; r < 4; ++r) accn[hp][j][r] += s[r] * acc4[j][r];
            }
        }
    }
    float inv[4][4];
    #pragma unroll
    for (int h = 0; h < 4; ++h)
        #pragma unroll
        for (int r = 0; r < 4; ++r) inv[h][r] = 1.0f / accd[h][r];
    #pragma unroll
    for (int hp = 0; hp < 2; ++hp)
        #pragma unroll
        for (int j = 0; j < 4; ++j) {
            int col = (4 * hp + j) * 16 + lrow;
            float bb = bVlds[col];
            #pragma unroll
            for (int r = 0; r < 4; ++r)
                out[(size_t)(row0 + kgrp * 4 + r) * 384 + coloff + col] =
                    accn[hp][j][r] * inv[2 * hp + (j >> 1)][r] + bb;
        }
}

// ---------------- main fused kernel: 4 waves x 16 rows, grid 1024 = 4 blocks/CU resident ----------------
__global__ __launch_bounds__(256, 4)
void TrSFRNNAgent_fused(const float* __restrict__ own,
                        const float* __restrict__ ally,
                        const float* __restrict__ enemy,
                        const char* __restrict__ ws,
                        float* __restrict__ out)
{
    __shared__ __align__(16) char smem[REGION];
    const int tid = threadIdx.x, lane = tid & 63, wid = tid >> 6;
    const int row0 = blockIdx.x * 64 + wid * 16;
    const int lrow = lane & 15, kgrp = lane >> 4;
    const int arow = row0 + lrow;

    // issue phase-1 LDS staging right away; hides under phase-0 compute
    stage36(ws + WS_P1, smem, wid, lane);

    // ---------------- Phase 0: own_obs -> q (packed bf16, scale+bias folded) + own_feature ----------------
    unsigned qq[16];
    {
        short8 afr0[3];
        const float* ap = own + (size_t)arow * D_OWN;
        #pragma unroll
        for (int ks = 0; ks < 3; ++ks) {
            f32x4 a = *(const f32x4*)(ap + ks * 32 + kgrp * 8);
            f32x4 b = *(const f32x4*)(ap + ks * 32 + kgrp * 8 + 4);
            afr0[ks] = pack8(a, b);
        }
        f32x4 acc[16];
        #pragma unroll
        for (int t = 0; t < 16; ++t)
            #pragma unroll
            for (int r = 0; r < 4; ++r) acc[t][r] = 0.0f;
        const short* bp0 = (const short*)(ws + WS_P0);
        #pragma unroll
        for (int ks = 0; ks < 3; ++ks)
            #pragma unroll
            for (int t = 0; t < 16; ++t) {
                short8 bfr = *(const short8*)(bp0 + (size_t)((t * 3 + ks) * 64 + lane) * 8);
                acc[t] = __builtin_amdgcn_mfma_f32_16x16x32_bf16(afr0[ks], bfr, acc[t], 0, 0, 0);
            }
        const float* b0 = (const float*)(ws + WS_B0);
        const float scale = 0.17677669529663687f;   // 1/sqrt(32), folded into q
        #pragma unroll
        for (int t = 0; t < 8; ++t) {
            float bb = b0[t * 16 + lrow];
            float q0 = (acc[t][0] + bb) * scale, q1 = (acc[t][1] + bb) * scale;
            float q2 = (acc[t][2] + bb) * scale, q3 = (acc[t][3] + bb) * scale;
            qq[t * 2] = cvtpk(q0, q1); qq[t * 2 + 1] = cvtpk(q2, q3);
        }
        #pragma unroll
        for (int t = 0; t < 8; ++t) {
            float bb = b0[128 + t * 16 + lrow];
            #pragma unroll
            for (int r = 0; r < 4; ++r)
                out[(size_t)(row0 + kgrp * 4 + r) * 384 + t * 16 + lrow] = acc[8 + t][r] + bb;
        }
    }
    __syncthreads();   // phase-1 LDS ready (barrier drains global_load_lds)

    // ---------------- Phase 1: allies ----------------
    attn_phase<N_AL, D_AL, false>(ally, (const short*)smem, nullptr,
                                  (const float*)(smem + 32768), qq, out, row0, lane, 128);
    __syncthreads();                       // all waves done reading phase-1 LDS
    stage36(ws + WS_P2, smem, wid, lane);  // re-stage for phase 2
    __syncthreads();

    // ---------------- Phase 2: enemies (K=64 staged + k64 rank-1 via acc init) ----------------
    attn_phase<N_EN, D_EN, true>(enemy, (const short*)smem, (const float*)(smem + 32768),
                                 (const float*)(smem + 33792), qq, out, row0, lane, 256);
}

extern "C" void kernel_launch(void* const* d_in, const int* in_sizes, int n_in,
                              void* d_out, int out_size, void* d_ws, size_t ws_size,
                              hipStream_t stream)
{
    (void)in_sizes; (void)n_in; (void)out_size; (void)ws_size;
    const float* own   = (const float*)d_in[0];
    const float* ally  = (const float*)d_in[1];
    const float* enemy = (const float*)d_in[2];
    const float* Wq    = (const float*)d_in[3];
    const float* bq    = (const float*)d_in[4];
    const float* Wak   = (const float*)d_in[5];
    const float* Wav   = (const float*)d_in[7];
    const float* bav   = (const float*)d_in[8];
    const float* Wek   = (const float*)d_in[9];
    const float* Wev   = (const float*)d_in[11];
    const float* bev   = (const float*)d_in[12];
    const float* Wown  = (const float*)d_in[13];
    const float* bown  = (const float*)d_in[14];

    pack_weights<<<31, 256, 0, stream>>>(Wq, bq, Wak, Wav, bav, Wek, Wev, bev, Wown, bown,
                                         (char*)d_ws);
    TrSFRNNAgent_fused<<<BROWS / 64, 256, 0, stream>>>(own, ally, enemy,
                                                       (const char*)d_ws, (float*)d_out);
}